// Round 9
// baseline (224.680 us; speedup 1.0000x reference)
//
#include <hip/hip_runtime.h>
#include <hip/hip_bf16.h>

#define IMG 1024
#define OUTW 1018
#define RS 32                  // output rows owned per strip
#define NSTRIP 32              // 32*32 = 1024: strips tile rows exactly
#define NXW 4                  // waves across width: 4*256 = 1024 cols
#define NBATCH 16
#define NWAVE (NBATCH * NSTRIP * NXW)  // 2048 working waves
#define NBLK (NWAVE / 4)               // 512 blocks = exactly 2 blocks/CU, balanced
#define NSTEP (RS + 8)                 // 40 row-steps per strip
#define NTC ((NSTEP + 8) / 9)          // 5 outer ring cycles (45 slots, 5 skipped)
#define EPSF 2.2204460492503131e-16f
#define INV81 (1.0f / 81.0f)
#define LROW 1040              // 4-col left pad + 1024 cols + 12-col right pad

// HBM -> LDS direct (no VGPR round-trip). Per-lane global src; LDS dest =
// wave-uniform base + lane*16 (m97 pattern). size must be the literal 16.
__device__ __forceinline__ void gload16(const float* g, float* l) {
  __builtin_amdgcn_global_load_lds(
      (const __attribute__((address_space(1))) unsigned int*)g,
      (__attribute__((address_space(3))) unsigned int*)l, 16, 0, 0);
}

// Linear horizontal 9-sum window update (bf16 ring for exact cancel).
__device__ __forceinline__ void hsum_update(const float* __restrict__ arr,
                                            float* __restrict__ wX,
                                            __hip_bfloat162* __restrict__ g) {
  float h0 = arr[0] + arr[1] + arr[2] + arr[3] + arr[4] + arr[5] + arr[6] +
             arr[7] + arr[8];
  float h1 = h0 - arr[0] + arr[9];
  float h2 = h1 - arr[1] + arr[10];
  float h3 = h2 - arr[2] + arr[11];
  __hip_bfloat162 plo = __float22bfloat162_rn(make_float2(h0, h1));
  __hip_bfloat162 phi = __float22bfloat162_rn(make_float2(h2, h3));
  float2 nlo = __bfloat1622float2(plo), nhi = __bfloat1622float2(phi);
  float2 olo = __bfloat1622float2(g[0]), ohi = __bfloat1622float2(g[1]);
  wX[0] += nlo.x - olo.x;
  wX[1] += nlo.y - olo.y;
  wX[2] += nhi.x - ohi.x;
  wX[3] += nhi.y - ohi.y;
  g[0] = plo;
  g[1] = phi;
}

// Quadratic (a[p]*b[p]) horizontal 9-sum window update, fmaf-fused.
__device__ __forceinline__ void hsum_update_sq(const float* __restrict__ a,
                                               const float* __restrict__ b,
                                               float* __restrict__ wX,
                                               __hip_bfloat162* __restrict__ g) {
  float h0 = a[0] * b[0];
  h0 = fmaf(a[1], b[1], h0); h0 = fmaf(a[2], b[2], h0);
  h0 = fmaf(a[3], b[3], h0); h0 = fmaf(a[4], b[4], h0);
  h0 = fmaf(a[5], b[5], h0); h0 = fmaf(a[6], b[6], h0);
  h0 = fmaf(a[7], b[7], h0); h0 = fmaf(a[8], b[8], h0);
  float h1 = fmaf(a[9],  b[9],  fmaf(-a[0], b[0], h0));
  float h2 = fmaf(a[10], b[10], fmaf(-a[1], b[1], h1));
  float h3 = fmaf(a[11], b[11], fmaf(-a[2], b[2], h2));
  __hip_bfloat162 plo = __float22bfloat162_rn(make_float2(h0, h1));
  __hip_bfloat162 phi = __float22bfloat162_rn(make_float2(h2, h3));
  float2 nlo = __bfloat1622float2(plo), nhi = __bfloat1622float2(phi);
  float2 olo = __bfloat1622float2(g[0]), ohi = __bfloat1622float2(g[1]);
  wX[0] += nlo.x - olo.x;
  wX[1] += nlo.y - olo.y;
  wX[2] += nhi.x - ohi.x;
  wX[3] += nhi.y - ohi.y;
  g[0] = plo;
  g[1] = phi;
}

// VGPR MUST stay <=128 (cliff: 132-140 VGPR halves occupancy, rounds 6-8).
// This version holds NO cross-step data in registers: staging is HBM->LDS
// via global_load_lds (zero VGPR), halo+pad come from LDS (zero shuffles,
// zero edge selects). One barrier per step (m97 single-barrier structure);
// __syncthreads' implicit vmcnt(0) drain retires last step's prefetch.
__global__ __launch_bounds__(256, 1) void fused_kernel(
    const float* __restrict__ I, const float* __restrict__ J,
    double2* __restrict__ partial) {
  const int tid = threadIdx.x;
  const int lane = tid & 63;
  const int wv = tid >> 6;
  const int wid = blockIdx.x * 4 + wv;
  // 4 waves of a block = 4 xw-segments of the SAME (batch, strip) row.
  const int b = wid >> 7;                  // wid / 128
  const int rem = wid & 127;
  const int strip = rem >> 2;
  const int xw = rem & 3;                  // wave index = xw (block-local)
  const int R0 = strip * RS;
  const int base = xw * 256;               // wave's first column
  const int c0 = base + 4 * lane;          // lane's first owned column

  // [buf][img][4 pad + 1024 + 12 pad]; pads stay 0 -> conv zero-pad free.
  __shared__ __align__(16) float lds[2][2][LROW];
  for (int k = tid; k < 2 * 2 * LROW; k += 256) (&lds[0][0][0])[k] = 0.f;
  __syncthreads();                         // zeros visible before any staging

  const float* Ib = I + (size_t)b * (IMG * IMG);
  const float* Jb = J + (size_t)b * (IMG * IMG);

  float acc_cc = 0.f, acc_sm = 0.f;
  {
    // bf16-packed ring: 9 rows x 5 quantities x 4 cols = 90 VGPRs
    __hip_bfloat162 gI[9][2], gJ[9][2], gII[9][2], gJJ[9][2], gIJ[9][2];
    const __hip_bfloat162 z2 = __float22bfloat162_rn(make_float2(0.f, 0.f));
#pragma unroll
    for (int k = 0; k < 9; ++k) {
      gI[k][0] = z2; gI[k][1] = z2; gJ[k][0] = z2; gJ[k][1] = z2;
      gII[k][0] = z2; gII[k][1] = z2; gJJ[k][0] = z2; gJJ[k][1] = z2;
      gIJ[k][0] = z2; gIJ[k][1] = z2;
    }
    float wI[4] = {0,0,0,0}, wJ[4] = {0,0,0,0}, wII[4] = {0,0,0,0},
          wJJ[4] = {0,0,0,0}, wIJ[4] = {0,0,0,0};
    float prevI[4] = {0,0,0,0};

    // Prologue: stage row R0-1 into buf0 (strip 0 keeps zeros = top pad).
    if (R0 > 0) {                          // block-uniform
      const float* rpI = Ib + ((size_t)(R0 - 1) << 10);
      const float* rpJ = Jb + ((size_t)(R0 - 1) << 10);
      gload16(rpI + base + 4 * lane, &lds[0][0][4 + base]);
      gload16(rpJ + base + 4 * lane, &lds[0][1][4 + base]);
    }

    for (int tc = 0; tc < NTC; ++tc) {
#pragma unroll
      for (int u = 0; u < 9; ++u) {
        const int t = tc * 9 + u;
        if (t < NSTEP) {                   // block-uniform
          const int r = R0 - 1 + t;        // row staged in buf[cur]
          const int cur = t & 1;
          __syncthreads();  // drains my vmcnt -> buf[cur] complete everywhere;
                            // also all reads of buf[cur^1] from step t-1 done.

          // Prefetch row r+1 into buf[cur^1] (HBM->LDS, zero VGPR); retired
          // by next step's __syncthreads. Tail rows: stage zeros instead.
          if (t + 1 < NSTEP) {             // block-uniform
            const int rn = r + 1;          // >= 0 always
            float* dI = &lds[cur ^ 1][0][4 + base];
            float* dJ = &lds[cur ^ 1][1][4 + base];
            if (rn < IMG) {                // block-uniform
              gload16(Ib + ((size_t)rn << 10) + base + 4 * lane, dI);
              gload16(Jb + ((size_t)rn << 10) + base + 4 * lane, dJ);
            } else {
              const float4 z4 = make_float4(0.f, 0.f, 0.f, 0.f);
              *(float4*)(dI + 4 * lane) = z4;
              *(float4*)(dJ + 4 * lane) = z4;
            }
          }

          // Gather the 12-col window straight from LDS (idx = 4 + col).
          const float* LI = &lds[cur][0][0];
          const float* LJ = &lds[cur][1][0];
          float4 a0 = *(const float4*)(LI + c0);        // cols c0-4..c0-1
          float4 a1 = *(const float4*)(LI + c0 + 4);    // cols c0 ..c0+3
          float4 a2 = *(const float4*)(LI + c0 + 8);    // cols c0+4..c0+7
          float4 a3 = *(const float4*)(LI + c0 + 12);   // cols c0+8..c0+11
          float4 b0 = *(const float4*)(LJ + c0);
          float4 b1 = *(const float4*)(LJ + c0 + 4);
          float4 b2 = *(const float4*)(LJ + c0 + 8);
          float4 b3 = *(const float4*)(LJ + c0 + 12);
          float iw[12], jw[12];
          iw[0] = a0.w;
          iw[1] = a1.x; iw[2] = a1.y; iw[3] = a1.z; iw[4] = a1.w;
          iw[5] = a2.x; iw[6] = a2.y; iw[7] = a2.z; iw[8] = a2.w;
          iw[9] = a3.x; iw[10] = a3.y; iw[11] = a3.z;
          jw[0] = b0.w;
          jw[1] = b1.x; jw[2] = b1.y; jw[3] = b1.z; jw[4] = b1.w;
          jw[5] = b2.x; jw[6] = b2.y; jw[7] = b2.z; jw[8] = b2.w;
          jw[9] = b3.x; jw[10] = b3.y; jw[11] = b3.z;

          hsum_update(iw, wI, gI[u]);
          hsum_update(jw, wJ, gJ[u]);
          hsum_update_sq(iw, iw, wII, gII[u]);
          hsum_update_sq(jw, jw, wJJ, gJJ[u]);
          hsum_update_sq(iw, jw, wIJ, gIJ[u]);

          // smoothness dy: pairs (r-1, r) with r-1 owned by this strip
          if (r >= R0 + 1 && r <= R0 + RS && r <= IMG - 1) {   // uniform
#pragma unroll
            for (int q = 0; q < 4; ++q) {
              float d = iw[1 + q] - prevI[q];
              acc_sm = fmaf(d, d, acc_sm);
            }
          }
          // smoothness dx at owned rows
          if (r >= R0 && r <= R0 + RS - 1 && r <= IMG - 1) {   // uniform
#pragma unroll
            for (int q = 0; q < 4; ++q) {
              float d = iw[2 + q] - iw[1 + q];
              d = (c0 + q < IMG - 1) ? d : 0.f;
              acc_sm = fmaf(d, d, acc_sm);
            }
          }
          prevI[0] = iw[1]; prevI[1] = iw[2]; prevI[2] = iw[3]; prevI[3] = iw[4];

          // emit output row oy = R0 + t - 8 once window complete
          if (t >= 8) {                                        // uniform
            const int oy = R0 + t - 8;
            if (oy < OUTW) {                                   // uniform
#pragma unroll
              for (int q = 0; q < 4; ++q) {
                if (c0 + q < OUTW) {
                  float cross = fmaf(-(wI[q] * wJ[q]), INV81, wIJ[q]);
                  float iva   = fmaf(-(wI[q] * wI[q]), INV81, wII[q]);
                  float jva   = fmaf(-(wJ[q] * wJ[q]), INV81, wJJ[q]);
                  float den   = fmaf(iva, jva, EPSF);
                  acc_cc += cross * cross * __builtin_amdgcn_rcpf(den);
                }
              }
            }
          }
        }
      }
    }
  }

  // per-wave shuffle reduce, then per-block LDS reduce; one double2 per block
  float vc = acc_cc, vs = acc_sm;
#pragma unroll
  for (int off = 32; off > 0; off >>= 1) {
    vc += __shfl_down(vc, off);
    vs += __shfl_down(vs, off);
  }
  __shared__ double2 red[4];
  if (lane == 0) red[wv] = make_double2((double)vc, (double)vs);
  __syncthreads();
  if (tid == 0) {
    partial[blockIdx.x] = make_double2(red[0].x + red[1].x + red[2].x + red[3].x,
                                       red[0].y + red[1].y + red[2].y + red[3].y);
  }
}

__global__ __launch_bounds__(256) void fin_kernel(const double2* __restrict__ partial,
                                                  float* __restrict__ out) {
  double s_cc = 0.0, s_sm = 0.0;
  for (int i = threadIdx.x; i < NBLK; i += 256) {
    double2 p = partial[i];
    s_cc += p.x; s_sm += p.y;
  }
#pragma unroll
  for (int off = 32; off > 0; off >>= 1) {
    s_cc += __shfl_down(s_cc, off);
    s_sm += __shfl_down(s_sm, off);
  }
  __shared__ double r1[4], r2[4];
  if ((threadIdx.x & 63) == 0) { r1[threadIdx.x >> 6] = s_cc; r2[threadIdx.x >> 6] = s_sm; }
  __syncthreads();
  if (threadIdx.x == 0) {
    const double cc = (r1[0] + r1[1] + r1[2] + r1[3]) /
                      (double)((size_t)NBATCH * OUTW * OUTW);
    const double sm = (r2[0] + r2[1] + r2[2] + r2[3]) /
                      (2.0 * (double)((size_t)NBATCH * IMG * (IMG - 1)));
    out[0] = (float)(-cc + 0.1 * sm);
  }
}

extern "C" void kernel_launch(void* const* d_in, const int* in_sizes, int n_in,
                              void* d_out, int out_size, void* d_ws, size_t ws_size,
                              hipStream_t stream) {
  const float* y  = (const float*)d_in[0];
  const float* yt = (const float*)d_in[1];
  float* out = (float*)d_out;
  double2* partial = (double2*)d_ws;
  fused_kernel<<<NBLK, 256, 0, stream>>>(y, yt, partial);
  fin_kernel<<<1, 256, 0, stream>>>(partial, out);
}